// Round 1
// baseline (269.779 us; speedup 1.0000x reference)
//
#include <hip/hip_runtime.h>
#include <hip/hip_bf16.h>
#include <stdint.h>
#include <stddef.h>

// ---------------------------------------------------------------------------
// PAttention: y = softmax_band( (x Wq^T) K^T / 32 ) V,  band = |q-kv| < 512
// L = T = 8192, D = 1024. bf16 MFMA compute, fp32 accumulate/output.
// ---------------------------------------------------------------------------

typedef __bf16 bf16x8 __attribute__((ext_vector_type(8)));
typedef __bf16 bf16x4 __attribute__((ext_vector_type(4)));
typedef float  f32x4  __attribute__((ext_vector_type(4)));

constexpr int Lq   = 8192;   // query rows
constexpr int Tk   = 8192;   // kv rows
constexpr int Dd   = 1024;   // head dim
constexpr int WINW = 512;    // sliding window
constexpr int NQT  = 64;     // q-tiles of 128 rows
constexpr int BAND = 1152;   // banded kv span per q-tile (kv0 = 128t-512, 9*128)
constexpr int VTP  = 9344;   // padded Vt row: 512 + 8192 + 640 (all reads in-range)

// workspace layout (bytes)
constexpr size_t OFF_XB  = 0;                                   // x bf16      16 MB
constexpr size_t OFF_WQB = OFF_XB  + (size_t)Lq * Dd * 2;       // Wq bf16      2 MB
constexpr size_t OFF_QB  = OFF_WQB + (size_t)Dd * Dd * 2;       // Q bf16      16 MB
constexpr size_t OFF_KB  = OFF_QB  + (size_t)Lq * Dd * 2;       // K bf16      16 MB
constexpr size_t OFF_VT  = OFF_KB  + (size_t)Tk * Dd * 2;       // V^T bf16    19 MB
constexpr size_t OFF_S   = OFF_VT  + (size_t)Dd * VTP * 2;      // S fp32      38 MB
constexpr size_t OFF_P   = OFF_S   + (size_t)Lq * BAND * 4;     // P bf16      19 MB
constexpr size_t WS_NEED = OFF_P   + (size_t)Lq * BAND * 2;     // ~123 MB total

// ---------------------------------------------------------------------------
// async global->LDS, 16B per lane (lds dest is wave-uniform base + lane*16)
// ---------------------------------------------------------------------------
__device__ __forceinline__ void gload_lds16(const void* g, void* l) {
    __builtin_amdgcn_global_load_lds(
        (const __attribute__((address_space(1))) void*)g,
        (__attribute__((address_space(3))) void*)l, 16, 0, 0);
}

// ---------------------------------------------------------------------------
// 128x128 bt-GEMM core: C = A(MxK, row-major) * B(NxK, row-major)^T
// 256 threads = 4 waves (2x2), each wave 64x64 = 4x4 frags of 16x16.
// BK = 32, single-buffered LDS, 16x16x32 bf16 MFMA.
// ---------------------------------------------------------------------------
__device__ __forceinline__ void gemm_core(const __bf16* A, int lda,
                                          const __bf16* B, int ldb,
                                          int nK, f32x4 acc[4][4],
                                          __bf16* As, __bf16* Bs)
{
    const int tid  = threadIdx.x;
    const int wid  = tid >> 6;
    const int lane = tid & 63;
    const int wm   = wid >> 1, wn = wid & 1;
    const int srow = lane >> 2;          // staging row within 16-row group
    const int scol = (lane & 3) * 8;     // staging col (8 bf16 = 16B)
    const int fr   = lane & 15;          // fragment row
    const int kq   = (lane >> 4) * 8;    // fragment k offset

#pragma unroll
    for (int m = 0; m < 4; ++m)
#pragma unroll
        for (int n = 0; n < 4; ++n)
            acc[m][n] = 0.f;

    for (int k0 = 0; k0 < nK; k0 += 32) {
        // stage A,B tiles (128x32 bf16 each): wave w covers rows 32w..32w+31
#pragma unroll
        for (int j = 0; j < 2; ++j) {
            const int r = 32 * wid + 16 * j + srow;
            gload_lds16(A + (size_t)r * lda + (k0 + scol), As + (32 * wid + 16 * j) * 32);
            gload_lds16(B + (size_t)r * ldb + (k0 + scol), Bs + (32 * wid + 16 * j) * 32);
        }
        asm volatile("s_waitcnt vmcnt(0)" ::: "memory");
        __syncthreads();

        bf16x8 a[4], b[4];
#pragma unroll
        for (int m = 0; m < 4; ++m)
            a[m] = *(const bf16x8*)(As + (64 * wm + 16 * m + fr) * 32 + kq);
#pragma unroll
        for (int n = 0; n < 4; ++n)
            b[n] = *(const bf16x8*)(Bs + (64 * wn + 16 * n + fr) * 32 + kq);
#pragma unroll
        for (int m = 0; m < 4; ++m)
#pragma unroll
            for (int n = 0; n < 4; ++n)
                acc[m][n] = __builtin_amdgcn_mfma_f32_16x16x32_bf16(a[m], b[n], acc[m][n], 0, 0, 0);
        __syncthreads();
    }
}

// ---------------------------------------------------------------------------
// elementwise fp32 -> bf16 (RNE), 4 elems/thread/iter
// ---------------------------------------------------------------------------
__global__ __launch_bounds__(256) void kcvt4(const float* __restrict__ src,
                                             __bf16* __restrict__ dst, int n4)
{
    int i = blockIdx.x * 256 + threadIdx.x;
    const int stride = gridDim.x * 256;
    for (; i < n4; i += stride) {
        const float4 v = *(const float4*)(src + (size_t)i * 4);
        bf16x4 o = {(__bf16)v.x, (__bf16)v.y, (__bf16)v.z, (__bf16)v.w};
        *(bf16x4*)(dst + (size_t)i * 4) = o;
    }
}

__global__ __launch_bounds__(256) void kzero16(uint4* __restrict__ dst, int n)
{
    int i = blockIdx.x * 256 + threadIdx.x;
    const int stride = gridDim.x * 256;
    const uint4 z = {0u, 0u, 0u, 0u};
    for (; i < n; i += stride) dst[i] = z;
}

// ---------------------------------------------------------------------------
// V (8192x1024 f32, kv-major) -> Vt (1024 x VTP bf16, d-major, col = 512+kv)
// ---------------------------------------------------------------------------
__global__ __launch_bounds__(256) void ktransV(const float* __restrict__ V,
                                               __bf16* __restrict__ Vt)
{
    __shared__ float tile[64][65];
    const int kv0 = blockIdx.y * 64, d0 = blockIdx.x * 64;
    const int tid = threadIdx.x;
    const int r = tid >> 4, c = (tid & 15) * 4;
#pragma unroll
    for (int ph = 0; ph < 4; ++ph) {
        const float4 v = *(const float4*)(V + (size_t)(kv0 + 16 * ph + r) * Dd + d0 + c);
        tile[16 * ph + r][c + 0] = v.x;
        tile[16 * ph + r][c + 1] = v.y;
        tile[16 * ph + r][c + 2] = v.z;
        tile[16 * ph + r][c + 3] = v.w;
    }
    __syncthreads();
#pragma unroll
    for (int ph = 0; ph < 4; ++ph) {
        const int dr = 16 * ph + r;
        bf16x4 o = {(__bf16)tile[c + 0][dr], (__bf16)tile[c + 1][dr],
                    (__bf16)tile[c + 2][dr], (__bf16)tile[c + 3][dr]};
        *(bf16x4*)(Vt + (size_t)(d0 + dr) * VTP + 512 + kv0 + c) = o;
    }
}

// ---------------------------------------------------------------------------
// Q = x Wq^T   (M=8192, N=1024, K=1024), bf16 out
// ---------------------------------------------------------------------------
__global__ __launch_bounds__(256) void kqgemm(const __bf16* __restrict__ xb,
                                              const __bf16* __restrict__ wqb,
                                              __bf16* __restrict__ qb)
{
    __shared__ __bf16 As[128 * 32], Bs[128 * 32];
    const int mt = blockIdx.y, nt = blockIdx.x;
    f32x4 acc[4][4];
    gemm_core(xb + (size_t)mt * 128 * Dd, Dd, wqb + (size_t)nt * 128 * Dd, Dd, Dd, acc, As, Bs);

    const int lane = threadIdx.x & 63, wid = threadIdx.x >> 6;
    const int wm = wid >> 1, wn = wid & 1;
    const int rb = (lane >> 4) * 4, cb = lane & 15;
#pragma unroll
    for (int m = 0; m < 4; ++m)
#pragma unroll
        for (int n = 0; n < 4; ++n)
#pragma unroll
            for (int r = 0; r < 4; ++r) {
                const int row = mt * 128 + 64 * wm + 16 * m + rb + r;
                const int col = nt * 128 + 64 * wn + 16 * n + cb;
                qb[(size_t)row * Dd + col] = (__bf16)acc[m][n][r];
            }
}

// ---------------------------------------------------------------------------
// banded S = Q K^T * scale, masked (outside band / range -> -1e30), fp32 out
// grid: (9 kv-subtiles, 64 q-tiles). kv base of tile t = 128t - 512.
// out-of-range K reads stay inside ws (Qb before Kb, Vt after) -> safe garbage,
// masked by index check in epilogue.
// ---------------------------------------------------------------------------
__global__ __launch_bounds__(256) void ksgemm(const __bf16* __restrict__ qb,
                                              const __bf16* __restrict__ kb,
                                              float* __restrict__ S)
{
    __shared__ __bf16 As[128 * 32], Bs[128 * 32];
    const int t = blockIdx.y, jb = blockIdx.x;
    const int kvbase = 128 * t - 512 + 128 * jb;
    f32x4 acc[4][4];
    gemm_core(qb + (size_t)t * 128 * Dd, Dd, kb + (ptrdiff_t)kvbase * Dd, Dd, Dd, acc, As, Bs);

    const int lane = threadIdx.x & 63, wid = threadIdx.x >> 6;
    const int wm = wid >> 1, wn = wid & 1;
    const int rb = (lane >> 4) * 4, cb = lane & 15;
    const float scale = 0.03125f;  // 1024^-0.5
#pragma unroll
    for (int m = 0; m < 4; ++m)
#pragma unroll
        for (int n = 0; n < 4; ++n)
#pragma unroll
            for (int r = 0; r < 4; ++r) {
                const int rl = 64 * wm + 16 * m + rb + r;
                const int cl = 64 * wn + 16 * n + cb;
                const int q  = 128 * t + rl;
                const int kv = kvbase + cl;
                const int dd = q - kv;
                const bool ok = (kv >= 0) && (kv < Tk) && (dd < WINW) && (dd > -WINW);
                S[(size_t)q * BAND + 128 * jb + cl] = ok ? acc[m][n][r] * scale : -1e30f;
            }
}

// ---------------------------------------------------------------------------
// row softmax over the 1152-wide band, bf16 P out. one block per row.
// ---------------------------------------------------------------------------
__global__ __launch_bounds__(256) void ksoftmax(const float* __restrict__ S,
                                                __bf16* __restrict__ Pp)
{
    const int row = blockIdx.x;
    const float* s = S + (size_t)row * BAND;
    __bf16* p = Pp + (size_t)row * BAND;
    const int tid = threadIdx.x;
    const int lane = tid & 63, wid = tid >> 6;

    const float s0 = s[tid], s1 = s[tid + 256], s2 = s[tid + 512], s3 = s[tid + 768];
    const float s4 = (tid < 128) ? s[tid + 1024] : -1e30f;

    float m = fmaxf(fmaxf(fmaxf(s0, s1), fmaxf(s2, s3)), s4);
#pragma unroll
    for (int off = 32; off; off >>= 1) m = fmaxf(m, __shfl_xor(m, off));
    __shared__ float redm[4], reds[4];
    if (lane == 0) redm[wid] = m;
    __syncthreads();
    m = fmaxf(fmaxf(redm[0], redm[1]), fmaxf(redm[2], redm[3]));

    const float e0 = __expf(s0 - m), e1 = __expf(s1 - m);
    const float e2 = __expf(s2 - m), e3 = __expf(s3 - m);
    const float e4 = (tid < 128) ? __expf(s4 - m) : 0.f;
    float sum = e0 + e1 + e2 + e3 + e4;
#pragma unroll
    for (int off = 32; off; off >>= 1) sum += __shfl_xor(sum, off);
    if (lane == 0) reds[wid] = sum;
    __syncthreads();
    const float inv = 1.f / (reds[0] + reds[1] + reds[2] + reds[3]);

    p[tid]        = (__bf16)(e0 * inv);
    p[tid + 256]  = (__bf16)(e1 * inv);
    p[tid + 512]  = (__bf16)(e2 * inv);
    p[tid + 768]  = (__bf16)(e3 * inv);
    if (tid < 128) p[tid + 1024] = (__bf16)(e4 * inv);
}

// ---------------------------------------------------------------------------
// Y = P V over the band: A = P_t (128 x 1152), B = Vt rows (d-major), K=1152.
// Vt col base for tile t = 512 + (128t - 512) = 128t. fp32 out to d_out.
// ---------------------------------------------------------------------------
__global__ __launch_bounds__(256) void kpvgemm(const __bf16* __restrict__ Pp,
                                               const __bf16* __restrict__ Vt,
                                               float* __restrict__ out)
{
    __shared__ __bf16 As[128 * 32], Bs[128 * 32];
    const int t = blockIdx.y, nb = blockIdx.x;
    f32x4 acc[4][4];
    gemm_core(Pp + (size_t)t * 128 * BAND, BAND,
              Vt + (size_t)nb * 128 * VTP + 128 * t, VTP, BAND, acc, As, Bs);

    const int lane = threadIdx.x & 63, wid = threadIdx.x >> 6;
    const int wm = wid >> 1, wn = wid & 1;
    const int rb = (lane >> 4) * 4, cb = lane & 15;
#pragma unroll
    for (int m = 0; m < 4; ++m)
#pragma unroll
        for (int n = 0; n < 4; ++n)
#pragma unroll
            for (int r = 0; r < 4; ++r) {
                const int row = 128 * t + 64 * wm + 16 * m + rb + r;
                const int col = 128 * nb + 64 * wn + 16 * n + cb;
                out[(size_t)row * Dd + col] = acc[m][n][r];
            }
}

// ---------------------------------------------------------------------------
extern "C" void kernel_launch(void* const* d_in, const int* in_sizes, int n_in,
                              void* d_out, int out_size, void* d_ws, size_t ws_size,
                              hipStream_t stream)
{
    const float* x  = (const float*)d_in[0];
    const float* Wq = (const float*)d_in[1];
    const float* Pk = (const float*)d_in[2];
    const float* Pv = (const float*)d_in[3];
    float* out = (float*)d_out;

    if (ws_size < WS_NEED) return;  // insufficient scratch -> fail validation cleanly

    char* ws = (char*)d_ws;
    __bf16* xb  = (__bf16*)(ws + OFF_XB);
    __bf16* wqb = (__bf16*)(ws + OFF_WQB);
    __bf16* qb  = (__bf16*)(ws + OFF_QB);
    __bf16* kb  = (__bf16*)(ws + OFF_KB);
    __bf16* vt  = (__bf16*)(ws + OFF_VT);
    float*  S   = (float*)(ws + OFF_S);
    __bf16* Pp  = (__bf16*)(ws + OFF_P);

    // 1) converts + V transpose (+ zero-pad Vt)
    kcvt4<<<2048, 256, 0, stream>>>(x, xb, (Lq * Dd) / 4);
    kcvt4<<<512, 256, 0, stream>>>(Wq, wqb, (Dd * Dd) / 4);
    kcvt4<<<2048, 256, 0, stream>>>(Pk, kb, (Tk * Dd) / 4);
    kzero16<<<2048, 256, 0, stream>>>((uint4*)vt, (int)((size_t)Dd * VTP * 2 / 16));
    ktransV<<<dim3(Dd / 64, Tk / 64), 256, 0, stream>>>(Pv, vt);

    // 2) Q = x Wq^T
    kqgemm<<<dim3(Dd / 128, Lq / 128), 256, 0, stream>>>(xb, wqb, qb);

    // 3) banded scores
    ksgemm<<<dim3(BAND / 128, NQT), 256, 0, stream>>>(qb, kb, S);

    // 4) softmax
    ksoftmax<<<Lq, 256, 0, stream>>>(S, Pp);

    // 5) Y = P V
    kpvgemm<<<dim3(Dd / 128, NQT), 256, 0, stream>>>(Pp, vt, out);
}

// Round 3
// 252.523 us; speedup vs baseline: 1.0683x; 1.0683x over previous
//
#include <hip/hip_runtime.h>
#include <hip/hip_bf16.h>
#include <stdint.h>
#include <stddef.h>

// ---------------------------------------------------------------------------
// PAttention: y = softmax_band( (x Wq^T) K^T / 32 ) V,  band = |q-kv| < 512
// L = T = 8192, D = 1024. bf16 MFMA compute, fp32 accumulate/output.
// Unnormalized-exp formulation: P = exp(S/32) (no max-sub needed, |S|<~8),
// rowsum via atomics in sgemm epilogue, divide in pv epilogue.
// ---------------------------------------------------------------------------

typedef __bf16 bf16x8 __attribute__((ext_vector_type(8)));
typedef __bf16 bf16x4 __attribute__((ext_vector_type(4)));
typedef float  f32x4  __attribute__((ext_vector_type(4)));

constexpr int Lq   = 8192;
constexpr int Tk   = 8192;
constexpr int Dd   = 1024;
constexpr int WINW = 512;
constexpr int NQT  = 64;     // q-tiles of 128 rows
constexpr int BAND = 1152;   // banded kv span per q-tile (kv0 = 128t-512, 9*128)
constexpr int VTP  = 9344;   // padded Vt row: 512 + 8192 + 640

// workspace layout (bytes)
constexpr size_t OFF_XB  = 0;                                   // x bf16      16 MB
constexpr size_t OFF_WQB = OFF_XB  + (size_t)Lq * Dd * 2;       // Wq bf16      2 MB
constexpr size_t OFF_QB  = OFF_WQB + (size_t)Dd * Dd * 2;       // Q bf16      16 MB
constexpr size_t OFF_KB  = OFF_QB  + (size_t)Lq * Dd * 2;       // K bf16      16 MB
constexpr size_t OFF_VT  = OFF_KB  + (size_t)Tk * Dd * 2;       // V^T bf16    19 MB
constexpr size_t OFF_RS  = OFF_VT  + (size_t)Dd * VTP * 2;      // rowsum f32  32 KB
constexpr size_t OFF_P   = OFF_RS  + (size_t)Lq * 4;            // P bf16      19 MB
constexpr size_t WS_NEED = OFF_P   + (size_t)Lq * BAND * 2;     // ~88 MB

// ---------------------------------------------------------------------------
__device__ __forceinline__ void gload_lds16(const void* g, void* l) {
    __builtin_amdgcn_global_load_lds(
        (const __attribute__((address_space(1))) void*)g,
        (__attribute__((address_space(3))) void*)l, 16, 0, 0);
}

// XCD-chunked bijective swizzle (requires nwg % 8 == 0, cpx = nwg/8)
__device__ __forceinline__ int xcd_swz(int bid, int cpx) {
    return (bid & 7) * cpx + (bid >> 3);
}

// ---------------------------------------------------------------------------
// 128x128 bt-GEMM core, double-buffered 2-phase:
// C = A(MxK, row-major) * B(NxK, row-major)^T
// 256 threads = 4 waves (2x2), each wave 64x64 = 4x4 frags of 16x16.
// BK = 32. Prefetch tile t+1 issued before compute of tile t; single
// __syncthreads per step (its implicit vmcnt(0) drain completes prefetch).
// As/Bs: 2 buffers x 128x32 bf16 each (16 KB each array).
// ---------------------------------------------------------------------------
__device__ __forceinline__ void gemm_core(const __bf16* __restrict__ A, int lda,
                                          const __bf16* __restrict__ B, int ldb,
                                          int nK, f32x4 acc[4][4],
                                          __bf16* As, __bf16* Bs)
{
    const int tid  = threadIdx.x;
    const int wid  = tid >> 6;
    const int lane = tid & 63;
    const int wm   = wid >> 1, wn = wid & 1;
    const int srow = lane >> 2;          // staging row within 16-row group
    const int scol = (lane & 3) * 8;     // staging col (8 bf16 = 16B)
    const int fr   = lane & 15;          // fragment row
    const int kq   = (lane >> 4) * 8;    // fragment k offset

#pragma unroll
    for (int m = 0; m < 4; ++m)
#pragma unroll
        for (int n = 0; n < 4; ++n)
            acc[m][n] = 0.f;

    auto stage = [&](int k0, int buf) {
#pragma unroll
        for (int j = 0; j < 2; ++j) {
            const int r = 32 * wid + 16 * j + srow;
            __bf16* da = As + buf * 4096 + (32 * wid + 16 * j) * 32;
            __bf16* db = Bs + buf * 4096 + (32 * wid + 16 * j) * 32;
            gload_lds16(A + (size_t)r * lda + (k0 + scol), da);
            gload_lds16(B + (size_t)r * ldb + (k0 + scol), db);
        }
    };

    stage(0, 0);
    __syncthreads();                     // drains vmcnt(0): tile 0 resident
    int cur = 0;
    const int nt = nK >> 5;
    for (int t = 0; t < nt; ++t) {
        if (t + 1 < nt) stage((t + 1) << 5, cur ^ 1);  // prefetch in flight
        const __bf16* Ab = As + cur * 4096;
        const __bf16* Bb = Bs + cur * 4096;
        bf16x8 a[4], b[4];
#pragma unroll
        for (int m = 0; m < 4; ++m)
            a[m] = *(const bf16x8*)(Ab + (64 * wm + 16 * m + fr) * 32 + kq);
#pragma unroll
        for (int n = 0; n < 4; ++n)
            b[n] = *(const bf16x8*)(Bb + (64 * wn + 16 * n + fr) * 32 + kq);
#pragma unroll
        for (int m = 0; m < 4; ++m)
#pragma unroll
            for (int n = 0; n < 4; ++n)
                acc[m][n] = __builtin_amdgcn_mfma_f32_16x16x32_bf16(a[m], b[n], acc[m][n], 0, 0, 0);
        __syncthreads();                 // drains vmcnt(0): tile t+1 resident
        cur ^= 1;
    }
}

// ---------------------------------------------------------------------------
// fused fp32->bf16 converts for x, Wq, K; also zeroes the rowsum buffer
// ---------------------------------------------------------------------------
__global__ __launch_bounds__(256) void kcvt_all(const float* __restrict__ x,
                                                const float* __restrict__ wq,
                                                const float* __restrict__ pk,
                                                __bf16* __restrict__ xb,
                                                __bf16* __restrict__ wqb,
                                                __bf16* __restrict__ kb,
                                                float* __restrict__ rs)
{
    const int gid = blockIdx.x * 256 + threadIdx.x;
    const int stride = gridDim.x * 256;
    if (gid < Lq / 4) ((uint4*)rs)[gid] = uint4{0u, 0u, 0u, 0u};  // 8192 f32
    constexpr int NX4 = Lq * Dd / 4, NW4 = Dd * Dd / 4, NK4 = Tk * Dd / 4;
    for (int i = gid; i < NX4; i += stride) {
        const float4 v = *(const float4*)(x + (size_t)i * 4);
        *(bf16x4*)(xb + (size_t)i * 4) = bf16x4{(__bf16)v.x, (__bf16)v.y, (__bf16)v.z, (__bf16)v.w};
    }
    for (int i = gid; i < NW4; i += stride) {
        const float4 v = *(const float4*)(wq + (size_t)i * 4);
        *(bf16x4*)(wqb + (size_t)i * 4) = bf16x4{(__bf16)v.x, (__bf16)v.y, (__bf16)v.z, (__bf16)v.w};
    }
    for (int i = gid; i < NK4; i += stride) {
        const float4 v = *(const float4*)(pk + (size_t)i * 4);
        *(bf16x4*)(kb + (size_t)i * 4) = bf16x4{(__bf16)v.x, (__bf16)v.y, (__bf16)v.z, (__bf16)v.w};
    }
}

__global__ __launch_bounds__(256) void kzero16(uint4* __restrict__ dst, int n)
{
    int i = blockIdx.x * 256 + threadIdx.x;
    const int stride = gridDim.x * 256;
    const uint4 z = {0u, 0u, 0u, 0u};
    for (; i < n; i += stride) dst[i] = z;
}

// ---------------------------------------------------------------------------
// V (8192x1024 f32, kv-major) -> Vt (1024 x VTP bf16, d-major, col = 512+kv)
// ---------------------------------------------------------------------------
__global__ __launch_bounds__(256) void ktransV(const float* __restrict__ V,
                                               __bf16* __restrict__ Vt)
{
    __shared__ float tile[64][65];
    const int kv0 = blockIdx.y * 64, d0 = blockIdx.x * 64;
    const int tid = threadIdx.x;
    const int r = tid >> 4, c = (tid & 15) * 4;
#pragma unroll
    for (int ph = 0; ph < 4; ++ph) {
        const float4 v = *(const float4*)(V + (size_t)(kv0 + 16 * ph + r) * Dd + d0 + c);
        tile[16 * ph + r][c + 0] = v.x;
        tile[16 * ph + r][c + 1] = v.y;
        tile[16 * ph + r][c + 2] = v.z;
        tile[16 * ph + r][c + 3] = v.w;
    }
    __syncthreads();
#pragma unroll
    for (int ph = 0; ph < 4; ++ph) {
        const int dr = 16 * ph + r;
        bf16x4 o = {(__bf16)tile[c + 0][dr], (__bf16)tile[c + 1][dr],
                    (__bf16)tile[c + 2][dr], (__bf16)tile[c + 3][dr]};
        *(bf16x4*)(Vt + (size_t)(d0 + dr) * VTP + 512 + kv0 + c) = o;
    }
}

// ---------------------------------------------------------------------------
// Q = x Wq^T   (M=8192, N=1024, K=1024), bf16 out. 1-D grid 512, XCD swizzle.
// ---------------------------------------------------------------------------
__global__ __launch_bounds__(256) void kqgemm(const __bf16* __restrict__ xb,
                                              const __bf16* __restrict__ wqb,
                                              __bf16* __restrict__ qb)
{
    __shared__ __bf16 As[2 * 128 * 32], Bs[2 * 128 * 32];
    const int swz = xcd_swz(blockIdx.x, 64);
    const int mt = swz >> 3, nt = swz & 7;
    f32x4 acc[4][4];
    gemm_core(xb + (size_t)mt * 128 * Dd, Dd, wqb + (size_t)nt * 128 * Dd, Dd, Dd, acc, As, Bs);

    const int lane = threadIdx.x & 63, wid = threadIdx.x >> 6;
    const int wm = wid >> 1, wn = wid & 1;
    const int rb = (lane >> 4) * 4, cb = lane & 15;
#pragma unroll
    for (int m = 0; m < 4; ++m)
#pragma unroll
        for (int n = 0; n < 4; ++n)
#pragma unroll
            for (int r = 0; r < 4; ++r) {
                const int row = mt * 128 + 64 * wm + 16 * m + rb + r;
                const int col = nt * 128 + 64 * wn + 16 * n + cb;
                qb[(size_t)row * Dd + col] = (__bf16)acc[m][n][r];
            }
}

// ---------------------------------------------------------------------------
// banded P = exp(Q K^T * scale) (masked -> 0), bf16 out, + rowsum atomics.
// 1-D grid 576 = 64 q-tiles x 9 kv-subtiles, XCD swizzle. kv base = 128t-512.
// Out-of-range K reads stay inside ws (QB before KB, VT after) -> garbage that
// is never exponentiated (mask check), never multiplied by zero.
// ---------------------------------------------------------------------------
__global__ __launch_bounds__(256) void ksgemm(const __bf16* __restrict__ qb,
                                              const __bf16* __restrict__ kb,
                                              __bf16* __restrict__ Pp,
                                              float* __restrict__ rs)
{
    __shared__ __bf16 As[2 * 128 * 32], Bs[2 * 128 * 32];
    const int swz = xcd_swz(blockIdx.x, 72);
    const int t = swz / 9, jb = swz - 9 * t;
    const int kvbase = 128 * t - 512 + 128 * jb;
    f32x4 acc[4][4];
    gemm_core(qb + (size_t)t * 128 * Dd, Dd, kb + (ptrdiff_t)kvbase * Dd, Dd, Dd, acc, As, Bs);

    const int lane = threadIdx.x & 63, wid = threadIdx.x >> 6;
    const int wm = wid >> 1, wn = wid & 1;
    const int rb = (lane >> 4) * 4, cb = lane & 15;
    const float scale = 0.03125f;  // 1024^-0.5
#pragma unroll
    for (int m = 0; m < 4; ++m)
#pragma unroll
        for (int r = 0; r < 4; ++r) {
            const int rl = 64 * wm + 16 * m + rb + r;
            const int q  = 128 * t + rl;
            float rsum = 0.f;
#pragma unroll
            for (int n = 0; n < 4; ++n) {
                const int cl = 64 * wn + 16 * n + cb;
                const int kv = kvbase + cl;
                const int dd = q - kv;
                const bool ok = (kv >= 0) && (kv < Tk) && (dd < WINW) && (dd > -WINW);
                const float e = ok ? __expf(acc[m][n][r] * scale) : 0.f;
                Pp[(size_t)q * BAND + 128 * jb + cl] = (__bf16)e;
                rsum += e;
            }
            // reduce across the 16 lanes holding this row's columns
#pragma unroll
            for (int off = 1; off < 16; off <<= 1) rsum += __shfl_xor(rsum, off);
            if (cb == 0) atomicAdd(&rs[q], rsum);
        }
}

// ---------------------------------------------------------------------------
// Y = P V / rowsum over the band: A = P_t (128 x 1152), B = Vt rows, K=1152.
// Vt col base for tile t = 128t. 1-D grid 512, XCD swizzle. fp32 out.
// ---------------------------------------------------------------------------
__global__ __launch_bounds__(256) void kpvgemm(const __bf16* __restrict__ Pp,
                                               const __bf16* __restrict__ Vt,
                                               const float* __restrict__ rs,
                                               float* __restrict__ out)
{
    __shared__ __bf16 As[2 * 128 * 32], Bs[2 * 128 * 32];
    const int swz = xcd_swz(blockIdx.x, 64);
    const int t = swz >> 3, nb = swz & 7;
    f32x4 acc[4][4];
    gemm_core(Pp + (size_t)t * 128 * BAND, BAND,
              Vt + (size_t)nb * 128 * VTP + 128 * t, VTP, BAND, acc, As, Bs);

    const int lane = threadIdx.x & 63, wid = threadIdx.x >> 6;
    const int wm = wid >> 1, wn = wid & 1;
    const int rb = (lane >> 4) * 4, cb = lane & 15;
#pragma unroll
    for (int m = 0; m < 4; ++m)
#pragma unroll
        for (int r = 0; r < 4; ++r) {
            const int row = 128 * t + 64 * wm + 16 * m + rb + r;
            const float inv = 1.f / rs[row];
#pragma unroll
            for (int n = 0; n < 4; ++n) {
                const int col = 128 * nb + 64 * wn + 16 * n + cb;
                out[(size_t)row * Dd + col] = acc[m][n][r] * inv;
            }
        }
}

// ---------------------------------------------------------------------------
extern "C" void kernel_launch(void* const* d_in, const int* in_sizes, int n_in,
                              void* d_out, int out_size, void* d_ws, size_t ws_size,
                              hipStream_t stream)
{
    const float* x  = (const float*)d_in[0];
    const float* Wq = (const float*)d_in[1];
    const float* Pk = (const float*)d_in[2];
    const float* Pv = (const float*)d_in[3];
    float* out = (float*)d_out;

    if (ws_size < WS_NEED) return;

    char* ws = (char*)d_ws;
    __bf16* xb  = (__bf16*)(ws + OFF_XB);
    __bf16* wqb = (__bf16*)(ws + OFF_WQB);
    __bf16* qb  = (__bf16*)(ws + OFF_QB);
    __bf16* kb  = (__bf16*)(ws + OFF_KB);
    __bf16* vt  = (__bf16*)(ws + OFF_VT);
    float*  rs  = (float*)(ws + OFF_RS);
    __bf16* Pp  = (__bf16*)(ws + OFF_P);

    kcvt_all<<<2048, 256, 0, stream>>>(x, Wq, Pk, xb, wqb, kb, rs);
    kzero16<<<2048, 256, 0, stream>>>((uint4*)vt, (int)((size_t)Dd * VTP * 2 / 16));
    ktransV<<<dim3(Dd / 64, Tk / 64), 256, 0, stream>>>(Pv, vt);

    kqgemm<<<512, 256, 0, stream>>>(xb, wqb, qb);
    ksgemm<<<576, 256, 0, stream>>>(qb, kb, Pp, rs);
    kpvgemm<<<512, 256, 0, stream>>>(Pp, vt, rs, out);
}

// Round 4
// 233.000 us; speedup vs baseline: 1.1578x; 1.0838x over previous
//
#include <hip/hip_runtime.h>
#include <hip/hip_bf16.h>
#include <stdint.h>
#include <stddef.h>

// ---------------------------------------------------------------------------
// PAttention: y = softmax_band( (x Wq^T) K^T / 32 ) V,  band = |q-kv| < 512
// L = T = 8192, D = 1024. bf16 MFMA compute, fp32 accumulate/output.
// Unnormalized-exp: P = exp(S/32) (|S/32| small -> no max-sub needed),
// rowsum via atomics in sgemm epilogue, divide in pv epilogue.
// Round 4: 8-wave (512-thread) 128x128 GEMM blocks -> 16 waves/CU resident.
// ---------------------------------------------------------------------------

typedef __bf16 bf16x8 __attribute__((ext_vector_type(8)));
typedef __bf16 bf16x4 __attribute__((ext_vector_type(4)));
typedef float  f32x4  __attribute__((ext_vector_type(4)));

constexpr int Lq   = 8192;
constexpr int Tk   = 8192;
constexpr int Dd   = 1024;
constexpr int WINW = 512;
constexpr int NQT  = 64;     // q-tiles of 128 rows
constexpr int BAND = 1152;   // banded kv span per q-tile (kv0 = 128t-512, 9*128)
constexpr int VTP  = 9344;   // padded Vt row: 512 + 8192 + 640

// workspace layout (bytes)
constexpr size_t OFF_XB  = 0;                                   // x bf16      16 MB
constexpr size_t OFF_WQB = OFF_XB  + (size_t)Lq * Dd * 2;       // Wq bf16      2 MB
constexpr size_t OFF_QB  = OFF_WQB + (size_t)Dd * Dd * 2;       // Q bf16      16 MB
constexpr size_t OFF_KB  = OFF_QB  + (size_t)Lq * Dd * 2;       // K bf16      16 MB
constexpr size_t OFF_VT  = OFF_KB  + (size_t)Tk * Dd * 2;       // V^T bf16    19 MB
constexpr size_t OFF_RS  = OFF_VT  + (size_t)Dd * VTP * 2;      // rowsum f32  32 KB
constexpr size_t OFF_P   = OFF_RS  + (size_t)Lq * 4;            // P bf16      19 MB
constexpr size_t WS_NEED = OFF_P   + (size_t)Lq * BAND * 2;     // ~88 MB

// ---------------------------------------------------------------------------
__device__ __forceinline__ void gload_lds16(const void* g, void* l) {
    __builtin_amdgcn_global_load_lds(
        (const __attribute__((address_space(1))) void*)g,
        (__attribute__((address_space(3))) void*)l, 16, 0, 0);
}

// XCD-chunked bijective swizzle (requires nwg % 8 == 0, cpx = nwg/8)
__device__ __forceinline__ int xcd_swz(int bid, int cpx) {
    return (bid & 7) * cpx + (bid >> 3);
}

// ---------------------------------------------------------------------------
// 128x128 bt-GEMM core, 512 threads = 8 waves (4M x 2N), wave tile 32x64.
// C = A(MxK, row-major) * B(NxK, row-major)^T, BK = 32, double-buffered:
// prefetch of tile t+1 issued before compute of tile t; the single
// __syncthreads per step drains vmcnt(0) (prefetch resident) + protects reuse.
// Per thread per step: 1 gload_lds16 for A + 1 for B. 8 MFMA/wave/step.
// As/Bs: 2 buffers x 128x32 bf16 (8 KB) each -> 32 KB total LDS.
// ---------------------------------------------------------------------------
__device__ __forceinline__ void gemm_core8(const __bf16* __restrict__ A, int lda,
                                           const __bf16* __restrict__ B, int ldb,
                                           int nK, f32x4 acc[2][4],
                                           __bf16* As, __bf16* Bs)
{
    const int tid  = threadIdx.x;
    const int wid  = tid >> 6;           // 0..7
    const int lane = tid & 63;
    const int wm   = wid >> 1;           // 0..3: rows 32*wm
    const int wn   = wid & 1;            // 0..1: cols 64*wn
    const int srow = tid >> 2;           // 0..127 staging row
    const int scol = (tid & 3) * 8;      // staging col (8 bf16 = 16B)
    const int fr   = lane & 15;          // fragment row
    const int kq   = (lane >> 4) * 8;    // fragment k offset

#pragma unroll
    for (int m = 0; m < 2; ++m)
#pragma unroll
        for (int n = 0; n < 4; ++n)
            acc[m][n] = 0.f;

    auto stage = [&](int k0, int buf) {
        // wave w stages rows 16w..16w+15 (64 lanes x 16B = 1 KB, linear)
        __bf16* da = As + buf * 4096 + (wid << 9);
        __bf16* db = Bs + buf * 4096 + (wid << 9);
        gload_lds16(A + (size_t)srow * lda + (k0 + scol), da);
        gload_lds16(B + (size_t)srow * ldb + (k0 + scol), db);
    };

    stage(0, 0);
    __syncthreads();                     // drains vmcnt(0): tile 0 resident
    int cur = 0;
    const int nt = nK >> 5;
    for (int t = 0; t < nt; ++t) {
        if (t + 1 < nt) stage((t + 1) << 5, cur ^ 1);  // prefetch in flight
        const __bf16* Ab = As + cur * 4096;
        const __bf16* Bb = Bs + cur * 4096;
        bf16x8 a[2], b[4];
#pragma unroll
        for (int m = 0; m < 2; ++m)
            a[m] = *(const bf16x8*)(Ab + (32 * wm + 16 * m + fr) * 32 + kq);
#pragma unroll
        for (int n = 0; n < 4; ++n)
            b[n] = *(const bf16x8*)(Bb + (64 * wn + 16 * n + fr) * 32 + kq);
#pragma unroll
        for (int m = 0; m < 2; ++m)
#pragma unroll
            for (int n = 0; n < 4; ++n)
                acc[m][n] = __builtin_amdgcn_mfma_f32_16x16x32_bf16(a[m], b[n], acc[m][n], 0, 0, 0);
        __syncthreads();                 // drains vmcnt(0): tile t+1 resident
        cur ^= 1;
    }
}

// ---------------------------------------------------------------------------
// fused prep: fp32->bf16 converts for x, Wq, K + zero rowsum + zero Vt pads
// ---------------------------------------------------------------------------
__global__ __launch_bounds__(256) void kcvt_all(const float* __restrict__ x,
                                                const float* __restrict__ wq,
                                                const float* __restrict__ pk,
                                                __bf16* __restrict__ xb,
                                                __bf16* __restrict__ wqb,
                                                __bf16* __restrict__ kb,
                                                uint4* __restrict__ vt4,
                                                float* __restrict__ rs)
{
    const int gid = blockIdx.x * 256 + threadIdx.x;
    const int stride = gridDim.x * 256;
    const uint4 z = {0u, 0u, 0u, 0u};
    if (gid < Lq / 4) ((uint4*)rs)[gid] = z;  // 8192 f32 rowsums
    // Vt pad zeroing: per d-row, left pad = 64 uint4 (cols 0..511), right
    // pad = 80 uint4 (cols 8704..9343). 144 chunks/row, row pitch 1168.
    constexpr int NPAD = Dd * 144;
    for (int i = gid; i < NPAD; i += stride) {
        const int row = i / 144, j = i - row * 144;
        const int ch = (j < 64) ? j : (j + 1024);
        vt4[(size_t)row * 1168 + ch] = z;
    }
    constexpr int NX4 = Lq * Dd / 4, NW4 = Dd * Dd / 4, NK4 = Tk * Dd / 4;
    for (int i = gid; i < NX4; i += stride) {
        const float4 v = *(const float4*)(x + (size_t)i * 4);
        *(bf16x4*)(xb + (size_t)i * 4) = bf16x4{(__bf16)v.x, (__bf16)v.y, (__bf16)v.z, (__bf16)v.w};
    }
    for (int i = gid; i < NW4; i += stride) {
        const float4 v = *(const float4*)(wq + (size_t)i * 4);
        *(bf16x4*)(wqb + (size_t)i * 4) = bf16x4{(__bf16)v.x, (__bf16)v.y, (__bf16)v.z, (__bf16)v.w};
    }
    for (int i = gid; i < NK4; i += stride) {
        const float4 v = *(const float4*)(pk + (size_t)i * 4);
        *(bf16x4*)(kb + (size_t)i * 4) = bf16x4{(__bf16)v.x, (__bf16)v.y, (__bf16)v.z, (__bf16)v.w};
    }
}

// ---------------------------------------------------------------------------
// V (8192x1024 f32, kv-major) -> Vt (1024 x VTP bf16, d-major, col = 512+kv)
// ---------------------------------------------------------------------------
__global__ __launch_bounds__(256) void ktransV(const float* __restrict__ V,
                                               __bf16* __restrict__ Vt)
{
    __shared__ float tile[64][65];
    const int kv0 = blockIdx.y * 64, d0 = blockIdx.x * 64;
    const int tid = threadIdx.x;
    const int r = tid >> 4, c = (tid & 15) * 4;
#pragma unroll
    for (int ph = 0; ph < 4; ++ph) {
        const float4 v = *(const float4*)(V + (size_t)(kv0 + 16 * ph + r) * Dd + d0 + c);
        tile[16 * ph + r][c + 0] = v.x;
        tile[16 * ph + r][c + 1] = v.y;
        tile[16 * ph + r][c + 2] = v.z;
        tile[16 * ph + r][c + 3] = v.w;
    }
    __syncthreads();
#pragma unroll
    for (int ph = 0; ph < 4; ++ph) {
        const int dr = 16 * ph + r;
        bf16x4 o = {(__bf16)tile[c + 0][dr], (__bf16)tile[c + 1][dr],
                    (__bf16)tile[c + 2][dr], (__bf16)tile[c + 3][dr]};
        *(bf16x4*)(Vt + (size_t)(d0 + dr) * VTP + 512 + kv0 + c) = o;
    }
}

// ---------------------------------------------------------------------------
// Q = x Wq^T   (M=8192, N=1024, K=1024), bf16 out. 1-D grid 512, XCD swizzle.
// ---------------------------------------------------------------------------
__global__ __launch_bounds__(512) void kqgemm(const __bf16* __restrict__ xb,
                                              const __bf16* __restrict__ wqb,
                                              __bf16* __restrict__ qb)
{
    __shared__ __bf16 As[2 * 128 * 32], Bs[2 * 128 * 32];
    const int swz = xcd_swz(blockIdx.x, 64);
    const int mt = swz >> 3, nt = swz & 7;
    f32x4 acc[2][4];
    gemm_core8(xb + (size_t)mt * 128 * Dd, Dd, wqb + (size_t)nt * 128 * Dd, Dd, Dd, acc, As, Bs);

    const int lane = threadIdx.x & 63, wid = threadIdx.x >> 6;
    const int wm = wid >> 1, wn = wid & 1;
    const int rb = (lane >> 4) * 4, cb = lane & 15;
#pragma unroll
    for (int m = 0; m < 2; ++m)
#pragma unroll
        for (int n = 0; n < 4; ++n)
#pragma unroll
            for (int r = 0; r < 4; ++r) {
                const int row = mt * 128 + 32 * wm + 16 * m + rb + r;
                const int col = nt * 128 + 64 * wn + 16 * n + cb;
                qb[(size_t)row * Dd + col] = (__bf16)acc[m][n][r];
            }
}

// ---------------------------------------------------------------------------
// banded P = exp(Q K^T * scale) (masked -> 0), bf16 out, + rowsum atomics.
// 1-D grid 576 = 64 q-tiles x 9 kv-subtiles, XCD swizzle. kv base = 128t-512.
// Out-of-range K reads stay inside ws (QB before KB, VT after) -> garbage that
// is masked in the epilogue (never exponentiated).
// ---------------------------------------------------------------------------
__global__ __launch_bounds__(512) void ksgemm(const __bf16* __restrict__ qb,
                                              const __bf16* __restrict__ kb,
                                              __bf16* __restrict__ Pp,
                                              float* __restrict__ rs)
{
    __shared__ __bf16 As[2 * 128 * 32], Bs[2 * 128 * 32];
    const int swz = xcd_swz(blockIdx.x, 72);
    const int t = swz / 9, jb = swz - 9 * t;
    const int kvbase = 128 * t - 512 + 128 * jb;
    f32x4 acc[2][4];
    gemm_core8(qb + (size_t)t * 128 * Dd, Dd, kb + (ptrdiff_t)kvbase * Dd, Dd, Dd, acc, As, Bs);

    const int lane = threadIdx.x & 63, wid = threadIdx.x >> 6;
    const int wm = wid >> 1, wn = wid & 1;
    const int rb = (lane >> 4) * 4, cb = lane & 15;
    const float scale = 0.03125f;  // 1024^-0.5
#pragma unroll
    for (int m = 0; m < 2; ++m)
#pragma unroll
        for (int r = 0; r < 4; ++r) {
            const int rl = 32 * wm + 16 * m + rb + r;
            const int q  = 128 * t + rl;
            float rsum = 0.f;
#pragma unroll
            for (int n = 0; n < 4; ++n) {
                const int cl = 64 * wn + 16 * n + cb;
                const int kv = kvbase + cl;
                const int dd = q - kv;
                const bool ok = (kv >= 0) && (kv < Tk) && (dd < WINW) && (dd > -WINW);
                const float e = ok ? __expf(acc[m][n][r] * scale) : 0.f;
                Pp[(size_t)q * BAND + 128 * jb + cl] = (__bf16)e;
                rsum += e;
            }
#pragma unroll
            for (int off = 1; off < 16; off <<= 1) rsum += __shfl_xor(rsum, off);
            if (cb == 0) atomicAdd(&rs[q], rsum);
        }
}

// ---------------------------------------------------------------------------
// Y = P V / rowsum over the band: A = P_t (128 x 1152), B = Vt rows, K=1152.
// Vt col base for tile t = 128t. 1-D grid 512, XCD swizzle. fp32 out.
// ---------------------------------------------------------------------------
__global__ __launch_bounds__(512) void kpvgemm(const __bf16* __restrict__ Pp,
                                               const __bf16* __restrict__ Vt,
                                               const float* __restrict__ rs,
                                               float* __restrict__ out)
{
    __shared__ __bf16 As[2 * 128 * 32], Bs[2 * 128 * 32];
    const int swz = xcd_swz(blockIdx.x, 64);
    const int t = swz >> 3, nb = swz & 7;
    f32x4 acc[2][4];
    gemm_core8(Pp + (size_t)t * 128 * BAND, BAND,
               Vt + (size_t)nb * 128 * VTP + 128 * t, VTP, BAND, acc, As, Bs);

    const int lane = threadIdx.x & 63, wid = threadIdx.x >> 6;
    const int wm = wid >> 1, wn = wid & 1;
    const int rb = (lane >> 4) * 4, cb = lane & 15;
#pragma unroll
    for (int m = 0; m < 2; ++m)
#pragma unroll
        for (int r = 0; r < 4; ++r) {
            const int row = 128 * t + 32 * wm + 16 * m + rb + r;
            const float inv = 1.f / rs[row];
#pragma unroll
            for (int n = 0; n < 4; ++n) {
                const int col = 128 * nb + 64 * wn + 16 * n + cb;
                out[(size_t)row * Dd + col] = acc[m][n][r] * inv;
            }
        }
}

// ---------------------------------------------------------------------------
extern "C" void kernel_launch(void* const* d_in, const int* in_sizes, int n_in,
                              void* d_out, int out_size, void* d_ws, size_t ws_size,
                              hipStream_t stream)
{
    const float* x  = (const float*)d_in[0];
    const float* Wq = (const float*)d_in[1];
    const float* Pk = (const float*)d_in[2];
    const float* Pv = (const float*)d_in[3];
    float* out = (float*)d_out;

    if (ws_size < WS_NEED) return;

    char* ws = (char*)d_ws;
    __bf16* xb  = (__bf16*)(ws + OFF_XB);
    __bf16* wqb = (__bf16*)(ws + OFF_WQB);
    __bf16* qb  = (__bf16*)(ws + OFF_QB);
    __bf16* kb  = (__bf16*)(ws + OFF_KB);
    __bf16* vt  = (__bf16*)(ws + OFF_VT);
    float*  rs  = (float*)(ws + OFF_RS);
    __bf16* Pp  = (__bf16*)(ws + OFF_P);

    kcvt_all<<<2048, 256, 0, stream>>>(x, Wq, Pk, xb, wqb, kb, (uint4*)vt, rs);
    ktransV<<<dim3(Dd / 64, Tk / 64), 256, 0, stream>>>(Pv, vt);

    kqgemm<<<512, 512, 0, stream>>>(xb, wqb, qb);
    ksgemm<<<576, 512, 0, stream>>>(qb, kb, Pp, rs);
    kpvgemm<<<512, 512, 0, stream>>>(Pp, vt, rs, out);
}

// Round 6
// 229.178 us; speedup vs baseline: 1.1772x; 1.0167x over previous
//
#include <hip/hip_runtime.h>
#include <hip/hip_bf16.h>
#include <stdint.h>
#include <stddef.h>

// ---------------------------------------------------------------------------
// PAttention: y = softmax_band( (x Wq^T) K^T / 32 ) V,  band = |q-kv| < 512
// L = T = 8192, D = 1024. bf16 MFMA compute, fp32 accumulate/output.
// Unnormalized-exp: P = exp(S/32), rowsum atomics in sgemm, divide in pv.
// Round 5: counted-vmcnt 3-buffer pipeline (T4) in the GEMM core — loads stay
// in flight across barriers (s_waitcnt vmcnt(2) + raw s_barrier, never
// vmcnt(0) in steady state).
// ---------------------------------------------------------------------------

typedef __bf16 bf16x8 __attribute__((ext_vector_type(8)));
typedef __bf16 bf16x4 __attribute__((ext_vector_type(4)));
typedef float  f32x4  __attribute__((ext_vector_type(4)));

constexpr int Lq   = 8192;
constexpr int Tk   = 8192;
constexpr int Dd   = 1024;
constexpr int WINW = 512;
constexpr int NQT  = 64;     // q-tiles of 128 rows
constexpr int BAND = 1152;   // banded kv span per q-tile (kv0 = 128t-512, 9*128)
constexpr int VTP  = 9344;   // padded Vt row: 512 + 8192 + 640

// workspace layout (bytes)
constexpr size_t OFF_XB  = 0;                                   // x bf16      16 MB
constexpr size_t OFF_WQB = OFF_XB  + (size_t)Lq * Dd * 2;       // Wq bf16      2 MB
constexpr size_t OFF_QB  = OFF_WQB + (size_t)Dd * Dd * 2;       // Q bf16      16 MB
constexpr size_t OFF_KB  = OFF_QB  + (size_t)Lq * Dd * 2;       // K bf16      16 MB
constexpr size_t OFF_VT  = OFF_KB  + (size_t)Tk * Dd * 2;       // V^T bf16    19 MB
constexpr size_t OFF_RS  = OFF_VT  + (size_t)Dd * VTP * 2;      // rowsum f32  32 KB
constexpr size_t OFF_P   = OFF_RS  + (size_t)Lq * 4;            // P bf16      19 MB
constexpr size_t WS_NEED = OFF_P   + (size_t)Lq * BAND * 2;     // ~88 MB

// ---------------------------------------------------------------------------
__device__ __forceinline__ void gload_lds16(const void* g, void* l) {
    __builtin_amdgcn_global_load_lds(
        (const __attribute__((address_space(1))) void*)g,
        (__attribute__((address_space(3))) void*)l, 16, 0, 0);
}

// XCD-chunked bijective swizzle (requires nwg % 8 == 0, cpx = nwg/8)
__device__ __forceinline__ int xcd_swz(int bid, int cpx) {
    return (bid & 7) * cpx + (bid >> 3);
}

// ---------------------------------------------------------------------------
// 128x128 bt-GEMM core, 512 threads = 8 waves (4M x 2N), wave tile 32x64.
// C = A(MxK, row-major) * B(NxK, row-major)^T, BK = 32.
// T4 pipeline: 3 LDS buffers, stage(t+2) issued each iter, s_waitcnt vmcnt(2)
// (stage(t+1) landed, stage(t+2) in flight) + raw s_barrier per iter — no
// vmcnt(0) drain in the main loop. Requires nK/32 >= 3 (here 32 or 36).
// Per thread per stage: 1 gload_lds16 A + 1 B. 8 MFMA/thread/step.
// As/Bs: 3 buffers x 128x32 bf16 (8 KB) each -> 48 KB total LDS.
// ---------------------------------------------------------------------------
__device__ __forceinline__ void gemm_core8(const __bf16* __restrict__ A, int lda,
                                           const __bf16* __restrict__ B, int ldb,
                                           int nK, f32x4 acc[2][4],
                                           __bf16* As, __bf16* Bs)
{
    const int tid  = threadIdx.x;
    const int wid  = tid >> 6;           // 0..7
    const int lane = tid & 63;
    const int wm   = wid >> 1;           // 0..3: rows 32*wm
    const int wn   = wid & 1;            // 0..1: cols 64*wn
    const int srow = tid >> 2;           // 0..127 staging row
    const int scol = (tid & 3) * 8;      // staging col (8 bf16 = 16B)
    const int fr   = lane & 15;          // fragment row
    const int kq   = (lane >> 4) * 8;    // fragment k offset

#pragma unroll
    for (int m = 0; m < 2; ++m)
#pragma unroll
        for (int n = 0; n < 4; ++n)
            acc[m][n] = 0.f;

    auto stage = [&](int k0, int buf) {
        // wave w stages rows 16w..16w+15 (64 lanes x 16B = 1 KB, linear)
        __bf16* da = As + buf * 4096 + (wid << 9);
        __bf16* db = Bs + buf * 4096 + (wid << 9);
        gload_lds16(A + (size_t)srow * lda + (k0 + scol), da);
        gload_lds16(B + (size_t)srow * ldb + (k0 + scol), db);
    };

    const int nt = nK >> 5;              // >= 3 always here
    stage(0, 0);
    stage(32, 1);
    asm volatile("s_waitcnt vmcnt(2)" ::: "memory");   // tile 0 resident
    __builtin_amdgcn_s_barrier();
    __builtin_amdgcn_sched_barrier(0);

    int bc = 0;                          // buffer holding tile t
    for (int t = 0; t < nt; ++t) {
        const bool pf = (t + 2 < nt);
        if (pf) {
            const int bn = (bc == 0) ? 2 : bc - 1;     // (t+2) % 3
            stage((t + 2) << 5, bn);
        }
        const __bf16* Ab = As + bc * 4096;
        const __bf16* Bb = Bs + bc * 4096;
        bf16x8 a[2], b[4];
#pragma unroll
        for (int m = 0; m < 2; ++m)
            a[m] = *(const bf16x8*)(Ab + (32 * wm + 16 * m + fr) * 32 + kq);
#pragma unroll
        for (int n = 0; n < 4; ++n)
            b[n] = *(const bf16x8*)(Bb + (64 * wn + 16 * n + fr) * 32 + kq);
#pragma unroll
        for (int m = 0; m < 2; ++m)
#pragma unroll
            for (int n = 0; n < 4; ++n)
                acc[m][n] = __builtin_amdgcn_mfma_f32_16x16x32_bf16(a[m], b[n], acc[m][n], 0, 0, 0);
        if (t + 1 < nt) {
            // next tile must be resident; keep stage(t+2) in flight
            if (pf) asm volatile("s_waitcnt vmcnt(2)" ::: "memory");
            else    asm volatile("s_waitcnt vmcnt(0)" ::: "memory");
            __builtin_amdgcn_s_barrier();
            __builtin_amdgcn_sched_barrier(0);         // pin ds_reads below sync
        }
        bc = (bc == 2) ? 0 : bc + 1;
    }
}

// ---------------------------------------------------------------------------
// fused prep: fp32->bf16 converts for x, Wq, K + zero rowsum + zero Vt pads
// ---------------------------------------------------------------------------
__global__ __launch_bounds__(256) void kcvt_all(const float* __restrict__ x,
                                                const float* __restrict__ wq,
                                                const float* __restrict__ pk,
                                                __bf16* __restrict__ xb,
                                                __bf16* __restrict__ wqb,
                                                __bf16* __restrict__ kb,
                                                uint4* __restrict__ vt4,
                                                float* __restrict__ rs)
{
    const int gid = blockIdx.x * 256 + threadIdx.x;
    const int stride = gridDim.x * 256;
    const uint4 z = {0u, 0u, 0u, 0u};
    if (gid < Lq / 4) ((uint4*)rs)[gid] = z;  // 8192 f32 rowsums
    // Vt pad zeroing: per d-row, left pad = 64 uint4 (cols 0..511), right
    // pad = 80 uint4 (cols 8704..9343). 144 chunks/row, row pitch 1168.
    constexpr int NPAD = Dd * 144;
    for (int i = gid; i < NPAD; i += stride) {
        const int row = i / 144, j = i - row * 144;
        const int ch = (j < 64) ? j : (j + 1024);
        vt4[(size_t)row * 1168 + ch] = z;
    }
    constexpr int NX4 = Lq * Dd / 4, NW4 = Dd * Dd / 4, NK4 = Tk * Dd / 4;
    for (int i = gid; i < NX4; i += stride) {
        const float4 v = *(const float4*)(x + (size_t)i * 4);
        *(bf16x4*)(xb + (size_t)i * 4) = bf16x4{(__bf16)v.x, (__bf16)v.y, (__bf16)v.z, (__bf16)v.w};
    }
    for (int i = gid; i < NW4; i += stride) {
        const float4 v = *(const float4*)(wq + (size_t)i * 4);
        *(bf16x4*)(wqb + (size_t)i * 4) = bf16x4{(__bf16)v.x, (__bf16)v.y, (__bf16)v.z, (__bf16)v.w};
    }
    for (int i = gid; i < NK4; i += stride) {
        const float4 v = *(const float4*)(pk + (size_t)i * 4);
        *(bf16x4*)(kb + (size_t)i * 4) = bf16x4{(__bf16)v.x, (__bf16)v.y, (__bf16)v.z, (__bf16)v.w};
    }
}

// ---------------------------------------------------------------------------
// V (8192x1024 f32, kv-major) -> Vt (1024 x VTP bf16, d-major, col = 512+kv)
// ---------------------------------------------------------------------------
__global__ __launch_bounds__(256) void ktransV(const float* __restrict__ V,
                                               __bf16* __restrict__ Vt)
{
    __shared__ float tile[64][65];
    const int kv0 = blockIdx.y * 64, d0 = blockIdx.x * 64;
    const int tid = threadIdx.x;
    const int r = tid >> 4, c = (tid & 15) * 4;
#pragma unroll
    for (int ph = 0; ph < 4; ++ph) {
        const float4 v = *(const float4*)(V + (size_t)(kv0 + 16 * ph + r) * Dd + d0 + c);
        tile[16 * ph + r][c + 0] = v.x;
        tile[16 * ph + r][c + 1] = v.y;
        tile[16 * ph + r][c + 2] = v.z;
        tile[16 * ph + r][c + 3] = v.w;
    }
    __syncthreads();
#pragma unroll
    for (int ph = 0; ph < 4; ++ph) {
        const int dr = 16 * ph + r;
        bf16x4 o = {(__bf16)tile[c + 0][dr], (__bf16)tile[c + 1][dr],
                    (__bf16)tile[c + 2][dr], (__bf16)tile[c + 3][dr]};
        *(bf16x4*)(Vt + (size_t)(d0 + dr) * VTP + 512 + kv0 + c) = o;
    }
}

// ---------------------------------------------------------------------------
// Q = x Wq^T   (M=8192, N=1024, K=1024), bf16 out. 1-D grid 512, XCD swizzle.
// ---------------------------------------------------------------------------
__global__ __launch_bounds__(512) void kqgemm(const __bf16* __restrict__ xb,
                                              const __bf16* __restrict__ wqb,
                                              __bf16* __restrict__ qb)
{
    __shared__ __bf16 As[3 * 128 * 32], Bs[3 * 128 * 32];
    const int swz = xcd_swz(blockIdx.x, 64);
    const int mt = swz >> 3, nt = swz & 7;
    f32x4 acc[2][4];
    gemm_core8(xb + (size_t)mt * 128 * Dd, Dd, wqb + (size_t)nt * 128 * Dd, Dd, Dd, acc, As, Bs);

    const int lane = threadIdx.x & 63, wid = threadIdx.x >> 6;
    const int wm = wid >> 1, wn = wid & 1;
    const int rb = (lane >> 4) * 4, cb = lane & 15;
#pragma unroll
    for (int m = 0; m < 2; ++m)
#pragma unroll
        for (int n = 0; n < 4; ++n)
#pragma unroll
            for (int r = 0; r < 4; ++r) {
                const int row = mt * 128 + 32 * wm + 16 * m + rb + r;
                const int col = nt * 128 + 64 * wn + 16 * n + cb;
                qb[(size_t)row * Dd + col] = (__bf16)acc[m][n][r];
            }
}

// ---------------------------------------------------------------------------
// banded P = exp(Q K^T * scale) (masked -> 0), bf16 out, + rowsum atomics.
// 1-D grid 576 = 64 q-tiles x 9 kv-subtiles, XCD swizzle. kv base = 128t-512.
// Out-of-range K reads stay inside ws (QB before KB, VT after) -> garbage that
// is masked in the epilogue (never exponentiated).
// ---------------------------------------------------------------------------
__global__ __launch_bounds__(512) void ksgemm(const __bf16* __restrict__ qb,
                                              const __bf16* __restrict__ kb,
                                              __bf16* __restrict__ Pp,
                                              float* __restrict__ rs)
{
    __shared__ __bf16 As[3 * 128 * 32], Bs[3 * 128 * 32];
    const int swz = xcd_swz(blockIdx.x, 72);
    const int t = swz / 9, jb = swz - 9 * t;
    const int kvbase = 128 * t - 512 + 128 * jb;
    f32x4 acc[2][4];
    gemm_core8(qb + (size_t)t * 128 * Dd, Dd, kb + (ptrdiff_t)kvbase * Dd, Dd, Dd, acc, As, Bs);

    const int lane = threadIdx.x & 63, wid = threadIdx.x >> 6;
    const int wm = wid >> 1, wn = wid & 1;
    const int rb = (lane >> 4) * 4, cb = lane & 15;
    const float scale = 0.03125f;  // 1024^-0.5
#pragma unroll
    for (int m = 0; m < 2; ++m)
#pragma unroll
        for (int r = 0; r < 4; ++r) {
            const int rl = 32 * wm + 16 * m + rb + r;
            const int q  = 128 * t + rl;
            float rsum = 0.f;
#pragma unroll
            for (int n = 0; n < 4; ++n) {
                const int cl = 64 * wn + 16 * n + cb;
                const int kv = kvbase + cl;
                const int dd = q - kv;
                const bool ok = (kv >= 0) && (kv < Tk) && (dd < WINW) && (dd > -WINW);
                const float e = ok ? __expf(acc[m][n][r] * scale) : 0.f;
                Pp[(size_t)q * BAND + 128 * jb + cl] = (__bf16)e;
                rsum += e;
            }
#pragma unroll
            for (int off = 1; off < 16; off <<= 1) rsum += __shfl_xor(rsum, off);
            if (cb == 0) atomicAdd(&rs[q], rsum);
        }
}

// ---------------------------------------------------------------------------
// Y = P V / rowsum over the band: A = P_t (128 x 1152), B = Vt rows, K=1152.
// Vt col base for tile t = 128t. 1-D grid 512, XCD swizzle. fp32 out.
// ---------------------------------------------------------------------------
__global__ __launch_bounds__(512) void kpvgemm(const __bf16* __restrict__ Pp,
                                               const __bf16* __restrict__ Vt,
                                               const float* __restrict__ rs,
                                               float* __restrict__ out)
{
    __shared__ __bf16 As[3 * 128 * 32], Bs[3 * 128 * 32];
    const int swz = xcd_swz(blockIdx.x, 64);
    const int t = swz >> 3, nb = swz & 7;
    f32x4 acc[2][4];
    gemm_core8(Pp + (size_t)t * 128 * BAND, BAND,
               Vt + (size_t)nb * 128 * VTP + 128 * t, VTP, BAND, acc, As, Bs);

    const int lane = threadIdx.x & 63, wid = threadIdx.x >> 6;
    const int wm = wid >> 1, wn = wid & 1;
    const int rb = (lane >> 4) * 4, cb = lane & 15;
#pragma unroll
    for (int m = 0; m < 2; ++m)
#pragma unroll
        for (int r = 0; r < 4; ++r) {
            const int row = 128 * t + 32 * wm + 16 * m + rb + r;
            const float inv = 1.f / rs[row];
#pragma unroll
            for (int n = 0; n < 4; ++n) {
                const int col = 128 * nb + 64 * wn + 16 * n + cb;
                out[(size_t)row * Dd + col] = acc[m][n][r] * inv;
            }
        }
}

// ---------------------------------------------------------------------------
extern "C" void kernel_launch(void* const* d_in, const int* in_sizes, int n_in,
                              void* d_out, int out_size, void* d_ws, size_t ws_size,
                              hipStream_t stream)
{
    const float* x  = (const float*)d_in[0];
    const float* Wq = (const float*)d_in[1];
    const float* Pk = (const float*)d_in[2];
    const float* Pv = (const float*)d_in[3];
    float* out = (float*)d_out;

    if (ws_size < WS_NEED) return;

    char* ws = (char*)d_ws;
    __bf16* xb  = (__bf16*)(ws + OFF_XB);
    __bf16* wqb = (__bf16*)(ws + OFF_WQB);
    __bf16* qb  = (__bf16*)(ws + OFF_QB);
    __bf16* kb  = (__bf16*)(ws + OFF_KB);
    __bf16* vt  = (__bf16*)(ws + OFF_VT);
    float*  rs  = (float*)(ws + OFF_RS);
    __bf16* Pp  = (__bf16*)(ws + OFF_P);

    kcvt_all<<<2048, 256, 0, stream>>>(x, Wq, Pk, xb, wqb, kb, (uint4*)vt, rs);
    ktransV<<<dim3(Dd / 64, Tk / 64), 256, 0, stream>>>(Pv, vt);

    kqgemm<<<512, 512, 0, stream>>>(xb, wqb, qb);
    ksgemm<<<576, 512, 0, stream>>>(qb, kb, Pp, rs);
    kpvgemm<<<512, 512, 0, stream>>>(Pp, vt, rs, out);
}